// Round 11
// baseline (1127.491 us; speedup 1.0000x reference)
//
#include <hip/hip_runtime.h>
#include <math.h>

#define N 4096
#define DIM 64
#define MAX_ITER 50
#define EPS 0.1f
#define THRESH 0.1f

// exp2/log2 domain constants. Note SV_SCALE * EPS_LN2 == 1 exactly (in exact
// arithmetic): v is kept PRE-SCALED in ws, combine epilogue is targs-(m+log2 s).
#define SV_SCALE 14.4269504088896340f  // (1/eps) * log2(e)
#define EPS_LN2 0.0693147180559945f    // eps * ln(2)

// gfx950 native transcendentals: v_exp_f32 IS 2^x, v_log_f32 IS log2
#define EXP2F(x) __builtin_amdgcn_exp2f(x)
#define LOG2F(x) __builtin_amdgcn_logf(x)

// 256 blocks x 1024 threads (16 waves), wave-per-row, 16 rows/block, 1 block/CU.
// Each wave PINS its 16KB C row in 64 VGPRs for the whole kernel; both phases
// compute from registers (u: row-LSE; v: LDS-transpose partials + cross-block
// combine). Barrier: single-hop all-to-all with parity-double-buffered payload
// flags (fast blocks may re-arm their flag for barrier G+1 while slow blocks
// still read G -> parity slots make G's payload stable until G+2).
#define NBLK 256
#define TPB 1024
#define WAVES 16

// ws layout (floats): v[4096] (scaled domain) + 2 x 256 x 8B flag slots.
#define WS_V 0
#define WS_FLAGS N
#define WS_TOTAL (N + 4 * NBLK)

// opaque keep-alive: values become non-rematerializable register residents
#define PIN4(v) asm volatile("" : "+v"(v.x), "+v"(v.y), "+v"(v.z), "+v"(v.w))

// ---------------- init: zero v + flag slots ----------------
__global__ void init_ws(float* __restrict__ ws) {
    int i = blockIdx.x * 256 + threadIdx.x;
    if (i < WS_TOTAL) ws[i] = 0.0f;
}

// ---------------- build D[i][j] = sum_d (A[i][d]-B[j][d])^2 ----------------
__global__ __launch_bounds__(256) void build_dist(const float* __restrict__ A,
                                                  const float* __restrict__ B,
                                                  float* __restrict__ Dst) {
    __shared__ float As[64][68];
    __shared__ float Bs[64][68];
    const int i0 = blockIdx.y << 6, j0 = blockIdx.x << 6;
    const int t = threadIdx.x;
    const float* Ag = A + (size_t)i0 * DIM;
    const float* Bg = B + (size_t)j0 * DIM;
    for (int k = t; k < 4096; k += 256) {
        As[k >> 6][k & 63] = Ag[k];
        Bs[k >> 6][k & 63] = Bg[k];
    }
    __syncthreads();
    const int ty = t >> 4, tx = t & 15;
    float acc[4][4] = {{0.f}};
    for (int d = 0; d < DIM; d += 4) {
        float4 av[4], bv[4];
#pragma unroll
        for (int a = 0; a < 4; ++a) av[a] = *(const float4*)&As[ty + 16 * a][d];
#pragma unroll
        for (int b = 0; b < 4; ++b) bv[b] = *(const float4*)&Bs[tx + 16 * b][d];
#pragma unroll
        for (int a = 0; a < 4; ++a)
#pragma unroll
            for (int b = 0; b < 4; ++b) {
                float d0 = av[a].x - bv[b].x;
                float d1 = av[a].y - bv[b].y;
                float d2 = av[a].z - bv[b].z;
                float d3 = av[a].w - bv[b].w;
                acc[a][b] = fmaf(d0, d0, acc[a][b]);
                acc[a][b] = fmaf(d1, d1, acc[a][b]);
                acc[a][b] = fmaf(d2, d2, acc[a][b]);
                acc[a][b] = fmaf(d3, d3, acc[a][b]);
            }
    }
#pragma unroll
    for (int a = 0; a < 4; ++a) {
        int i = i0 + ty + 16 * a;
        float* drow = Dst + (size_t)i * N + j0;
#pragma unroll
        for (int b = 0; b < 4; ++b) drow[tx + 16 * b] = acc[a][b];
    }
}

// ------ single-hop all-to-all grid barrier, payload-carrying, parity slots ----
// Arrive: one 8B relaxed-agent store (gen, blockPartial) to slot[G&1][b].
// Every block's wave 0 polls ALL 256 flags (4 coalesced loads/lane) and
// reduces the payload locally -> one L3 hop on the critical path, identical
// sum in every block (bitwise: same 256 values, same order -> uniform break).
__device__ __forceinline__ float grid_sync(float* ws, int b, int t, unsigned G,
                                           const float* red2, float* bcast) {
    __syncthreads();  // every wave drained (vmcnt 0) before the flag store
    unsigned long long* fl =
        (unsigned long long*)(ws + WS_FLAGS) + (size_t)(G & 1u) * NBLK;
    if (t == 0) {
        float s = 0.f;
#pragma unroll
        for (int i = 0; i < WAVES; ++i) s += red2[i];
        unsigned long long pk = (unsigned long long)G |
                                ((unsigned long long)__float_as_uint(s) << 32);
        __hip_atomic_store(fl + b, pk, __ATOMIC_RELAXED,
                           __HIP_MEMORY_SCOPE_AGENT);
    }
    if (t < 64) {  // wave 0 polls
        float sum;
        for (;;) {
            bool ok = true;
            sum = 0.f;
#pragma unroll
            for (int j = 0; j < NBLK / 64; ++j) {
                unsigned long long q =
                    __hip_atomic_load(fl + (t + 64 * j), __ATOMIC_RELAXED,
                                      __HIP_MEMORY_SCOPE_AGENT);
                ok = ok && ((unsigned)q >= G);
                sum += __uint_as_float((unsigned)(q >> 32));
            }
            if (__all(ok)) break;
            __builtin_amdgcn_s_sleep(1);
        }
#pragma unroll
        for (int off = 32; off; off >>= 1) sum += __shfl_xor(sum, off);
        if (t == 0) *bcast = sum;
    }
    __syncthreads();
    return *bcast;
}

// ------- stage the (pre-scaled) v vector into LDS: pure copy -------
__device__ __forceinline__ void stage(const float* __restrict__ src,
                                      float* __restrict__ sv, int t) {
    const unsigned long long* s8 = (const unsigned long long*)src;
#pragma unroll
    for (int i = 0; i < 2; ++i) {
        int idx = t + TPB * i;  // 0..2047
        unsigned long long q = __hip_atomic_load(s8 + idx, __ATOMIC_RELAXED,
                                                 __HIP_MEMORY_SCOPE_AGENT);
        sv[2 * idx] = __uint_as_float((unsigned)q);
        sv[2 * idx + 1] = __uint_as_float((unsigned)(q >> 32));
    }
}

// ---- u-phase: row LSE from the PINNED register row (zero memory traffic) ----
__device__ __forceinline__ float phasePinned(const float4 (&cR)[16],
                                             const float* __restrict__ sv,
                                             int lane, float target) {
    const float4* __restrict__ svv = (const float4*)sv;
    float m = -3.0e38f, s = 0.f;
#pragma unroll
    for (int g = 0; g < 4; ++g) {
        float d[16];
#pragma unroll
        for (int k = 0; k < 4; ++k) {
            float4 w = svv[lane + 64 * (4 * g + k)];
            d[4 * k + 0] = fmaf(cR[4 * g + k].x, -SV_SCALE, w.x);
            d[4 * k + 1] = fmaf(cR[4 * g + k].y, -SV_SCALE, w.y);
            d[4 * k + 2] = fmaf(cR[4 * g + k].z, -SV_SCALE, w.z);
            d[4 * k + 3] = fmaf(cR[4 * g + k].w, -SV_SCALE, w.w);
        }
        float m4[4];
#pragma unroll
        for (int k = 0; k < 4; ++k)
            m4[k] = fmaxf(fmaxf(d[4 * k], d[4 * k + 1]),
                          fmaxf(d[4 * k + 2], d[4 * k + 3]));
        float mg = fmaxf(fmaxf(m4[0], m4[1]), fmaxf(m4[2], m4[3]));
        float mn = fmaxf(m, mg);
        float ps = 0.f;
#pragma unroll
        for (int k = 0; k < 16; ++k) ps += EXP2F(d[k] - mn);
        s = fmaf(s, EXP2F(m - mn), ps);
        m = mn;
    }
#pragma unroll
    for (int off = 32; off; off >>= 1) {
        float mo = __shfl_xor(m, off);
        float so = __shfl_xor(s, off);
        float mn = fmaxf(m, mo);
        s = fmaf(s, EXP2F(m - mn), so * EXP2F(mo - mn));
        m = mn;
    }
    return fmaf(-EPS_LN2, m + LOG2F(s), target);
}

// ---------------- persistent kernel: all iterations + final ----------------
__global__ __launch_bounds__(TPB)
__attribute__((amdgpu_waves_per_eu(4, 4)))  // authorize the 128-VGPR tier
void sinkhorn_persist(
    const float* __restrict__ Cm, float* __restrict__ ws,
    float* __restrict__ out, float target) {
    __shared__ float sv[N];              // 16 KB staged (scaled) v
    __shared__ float4 bufA[WAVES][256];  // 64 KB transpose ping
    __shared__ float4 bufB[WAVES][256];  // 64 KB transpose pong
    __shared__ float us_lds[WAVES];
    __shared__ float red2[WAVES];
    __shared__ float bcast;
    float* v = ws + WS_V;
    unsigned long long* P8 = (unsigned long long*)(out + 1);  // 8MB partials
    const int t = threadIdx.x;
    const int b = blockIdx.x;
    const int lane = t & 63, wv = t >> 6;
    const int row = (b << 4) + wv;  // this wave's row
    const float targs = target * SV_SCALE;
    unsigned G = 1;
    float errv = 1e30f;
    float uprev = 0.f, un = 0.f;

    // prologue: load this wave's C row ONCE; pin it for the whole kernel.
    float4 cR[16];
    {
        const float4* __restrict__ crow = (const float4*)(Cm + (size_t)row * N);
#pragma unroll
        for (int k = 0; k < 16; ++k) cR[k] = crow[lane + 64 * k];
#pragma unroll
        for (int k = 0; k < 16; ++k) PIN4(cR[k]);
    }

    for (int it = 0; it < MAX_ITER; ++it) {
        // ---- u-phase: zero memory traffic ----
        stage(v, sv, t);
        __syncthreads();
        un = phasePinned(cR, sv, lane, target);
        if (lane == 0) {
            red2[wv] = fabsf(un - uprev);  // err contribution
            us_lds[wv] = un * SV_SCALE;    // share scaled u with block
        }
        uprev = un;
        __syncthreads();
        const float usw = us_lds[wv];

        // ---- v-partials: ping-pong LDS transpose of register rows ----
#pragma unroll
        for (int kk = 0; kk < 4; ++kk) {  // chunk 0 -> bufA
            float4 cc = cR[kk];
            float4 dd;
            dd.x = fmaf(cc.x, -SV_SCALE, usw);
            dd.y = fmaf(cc.y, -SV_SCALE, usw);
            dd.z = fmaf(cc.z, -SV_SCALE, usw);
            dd.w = fmaf(cc.w, -SV_SCALE, usw);
            bufA[wv][lane + 64 * kk] = dd;
        }
        __syncthreads();
        for (int c = 0; c < 4; ++c) {
            const float* bufs = (const float*)((c & 1) ? bufB : bufA);
            float val[16];
#pragma unroll
            for (int w2 = 0; w2 < 16; ++w2) val[w2] = bufs[w2 * 1024 + t];
            if (c < 3) {  // write next chunk to the other buffer meanwhile
                float4(*bw)[256] = (c & 1) ? bufA : bufB;
#pragma unroll
                for (int kk = 0; kk < 4; ++kk) {
                    float4 cc = cR[4 * (c + 1) + kk];
                    float4 dd;
                    dd.x = fmaf(cc.x, -SV_SCALE, usw);
                    dd.y = fmaf(cc.y, -SV_SCALE, usw);
                    dd.z = fmaf(cc.z, -SV_SCALE, usw);
                    dd.w = fmaf(cc.w, -SV_SCALE, usw);
                    bw[wv][lane + 64 * kk] = dd;
                }
            }
            float m = val[0];
#pragma unroll
            for (int w2 = 1; w2 < 16; ++w2) m = fmaxf(m, val[w2]);
            float s = 0.f;
#pragma unroll
            for (int w2 = 0; w2 < 16; ++w2) s += EXP2F(val[w2] - m);
            const int j = c * 1024 + t;  // this thread's column
            unsigned long long pk =
                (unsigned long long)__float_as_uint(m) |
                ((unsigned long long)__float_as_uint(s) << 32);
            __hip_atomic_store(
                P8 + ((size_t)(j >> 4) * NBLK + b) * 16 + (j & 15), pk,
                __ATOMIC_RELAXED, __HIP_MEMORY_SCOPE_AGENT);
            if (c < 3) __syncthreads();  // last chunk: grid_sync entry covers
        }
        errv = grid_sync(ws, b, t, G++, red2, &bcast);  // partials visible

        // ---- v-combine: block b owns columns 16b..16b+15; wave wv = one col
        {
            float m = -3.0e38f, s = 0.f;
#pragma unroll
            for (int i = 0; i < 4; ++i) {
                const int bb = lane + 64 * i;
                unsigned long long q = __hip_atomic_load(
                    P8 + ((size_t)b * NBLK + bb) * 16 + wv, __ATOMIC_RELAXED,
                    __HIP_MEMORY_SCOPE_AGENT);
                float mo = __uint_as_float((unsigned)q);
                float so = __uint_as_float((unsigned)(q >> 32));
                float mn = fmaxf(m, mo);
                s = fmaf(s, EXP2F(m - mn), so * EXP2F(mo - mn));
                m = mn;
            }
#pragma unroll
            for (int off = 32; off; off >>= 1) {
                float mo = __shfl_xor(m, off);
                float so = __shfl_xor(s, off);
                float mn = fmaxf(m, mo);
                s = fmaf(s, EXP2F(m - mn), so * EXP2F(mo - mn));
                m = mn;
            }
            if (lane == 0) {
                // scaled domain: vn' = targs - (m + log2 s)  [SV_SCALE*EPS_LN2==1]
                float vn = targs - (m + LOG2F(s));
                __hip_atomic_store(&v[16 * b + wv], vn, __ATOMIC_RELAXED,
                                   __HIP_MEMORY_SCOPE_AGENT);
                red2[wv] = 0.f;
            }
        }
        grid_sync(ws, b, t, G++, red2, &bcast);  // v visible everywhere
        // reference latches done AFTER applying this iteration's updates.
        if (errv < THRESH) break;  // uniform: identical sum in every block
    }

    // ---- final: pi = exp((u_i + v_j - C_ij)/eps), cost = sum(pi*C) ----
    // cR pinned; un is this wave's final u (all lanes). Partials region is
    // dead; pi plain stores overwrite out[1..N^2).
    stage(v, sv, t);
    __syncthreads();
    {
        float* pi = out + 1;
        const float ui = un * SV_SCALE;  // exp2-domain
        float4* __restrict__ prow = (float4*)(pi + (size_t)row * N);
        const float4* __restrict__ svv = (const float4*)sv;
        float csum = 0.f;
#pragma unroll
        for (int k = 0; k < 16; ++k) {
            const int f = lane + 64 * k;
            float4 c = cR[k];
            float4 w = svv[f];
            float4 p;
            p.x = EXP2F(fmaf(c.x, -SV_SCALE, ui + w.x));
            p.y = EXP2F(fmaf(c.y, -SV_SCALE, ui + w.y));
            p.z = EXP2F(fmaf(c.z, -SV_SCALE, ui + w.z));
            p.w = EXP2F(fmaf(c.w, -SV_SCALE, ui + w.w));
            prow[f] = p;
            csum = fmaf(p.x, c.x, csum);
            csum = fmaf(p.y, c.y, csum);
            csum = fmaf(p.z, c.z, csum);
            csum = fmaf(p.w, c.w, csum);
        }
#pragma unroll
        for (int off = 32; off; off >>= 1) csum += __shfl_xor(csum, off);
        if (lane == 0) red2[wv] = csum;
    }
    // cost rides the final barrier payload (every block computes the total).
    float ctot = grid_sync(ws, b, t, G++, red2, &bcast);
    if (b == 0 && t == 0) out[0] = ctot;
}

extern "C" void kernel_launch(void* const* d_in, const int* in_sizes, int n_in,
                              void* d_out, int out_size, void* d_ws, size_t ws_size,
                              hipStream_t stream) {
    const float* x = (const float*)d_in[0];  // [4096,64]
    const float* y = (const float*)d_in[1];  // [4096,64]
    float* out = (float*)d_out;              // [0]=cost, [1..N*N]=pi, [1+N*N..]=C
    float* C = out + 1 + (size_t)N * N;
    float* ws = (float*)d_ws;

    init_ws<<<dim3((WS_TOTAL + 255) / 256), dim3(256), 0, stream>>>(ws);

    dim3 bgrid(64, 64);
    build_dist<<<bgrid, dim3(256), 0, stream>>>(x, y, C);  // C[i][j] only

    float target = EPS * logf(1.0f / (float)N + 1e-8f);  // == eps*log_mu == eps*log_nu

    sinkhorn_persist<<<dim3(NBLK), dim3(TPB), 0, stream>>>(C, ws, out, target);
}

// Round 12
// 1040.697 us; speedup vs baseline: 1.0834x; 1.0834x over previous
//
#include <hip/hip_runtime.h>
#include <math.h>

#define N 4096
#define DIM 64
#define MAX_ITER 50
#define EPS 0.1f
#define THRESH 0.1f

// exp2/log2 domain constants. SV_SCALE * EPS_LN2 == 1 (exact): v is kept
// PRE-SCALED; combine epilogue is targs - (m + log2 s).
#define SV_SCALE 14.4269504088896340f  // (1/eps) * log2(e)
#define EPS_LN2 0.0693147180559945f    // eps * ln(2)

// gfx950 native transcendentals: v_exp_f32 IS 2^x, v_log_f32 IS log2
#define EXP2F(x) __builtin_amdgcn_exp2f(x)
#define LOG2F(x) __builtin_amdgcn_logf(x)

// 256 blocks x 1024 threads (16 waves), wave-per-row, 16 rows/block, 1 block/CU.
// Waves pin their 16KB C row in registers. ONE grid barrier per iteration
// (r10's two-hop scanner+replica design — all-to-all regressed in r11);
// v-visibility is flow-controlled: v entries are (tag,value) 8B pairs,
// consumers poll tags directly. Partials are parity-double-buffered.
#define NBLK 256
#define TPB 1024
#define WAVES 16
#define NREP 16  // wake replicas

// ws layout (floats): v = 4096 x (u32 tag, f32 scaled-value) 8B pairs,
// then barrier flags + replicas.
#define WS_V 0
#define WS_FLAGS (2 * N)                  // 256 x (u32 gen, f32 val) 8B pairs
#define WS_GGEN (2 * N + 2 * NBLK)        // 16 replicas x 16-word stride
#define WS_TOTAL (2 * N + 2 * NBLK + NREP * 16)

// opaque keep-alive: values become non-rematerializable register residents
#define PIN4(v) asm volatile("" : "+v"(v.x), "+v"(v.y), "+v"(v.z), "+v"(v.w))

// ---------------- init: zero v pairs (tag0,val0) + flags + replicas ----------
__global__ void init_ws(float* __restrict__ ws) {
    int i = blockIdx.x * 256 + threadIdx.x;
    if (i < WS_TOTAL) ws[i] = 0.0f;
}

// ---------------- build D[i][j] = sum_d (A[i][d]-B[j][d])^2 ----------------
__global__ __launch_bounds__(256) void build_dist(const float* __restrict__ A,
                                                  const float* __restrict__ B,
                                                  float* __restrict__ Dst) {
    __shared__ float As[64][68];
    __shared__ float Bs[64][68];
    const int i0 = blockIdx.y << 6, j0 = blockIdx.x << 6;
    const int t = threadIdx.x;
    const float* Ag = A + (size_t)i0 * DIM;
    const float* Bg = B + (size_t)j0 * DIM;
    for (int k = t; k < 4096; k += 256) {
        As[k >> 6][k & 63] = Ag[k];
        Bs[k >> 6][k & 63] = Bg[k];
    }
    __syncthreads();
    const int ty = t >> 4, tx = t & 15;
    float acc[4][4] = {{0.f}};
    for (int d = 0; d < DIM; d += 4) {
        float4 av[4], bv[4];
#pragma unroll
        for (int a = 0; a < 4; ++a) av[a] = *(const float4*)&As[ty + 16 * a][d];
#pragma unroll
        for (int b = 0; b < 4; ++b) bv[b] = *(const float4*)&Bs[tx + 16 * b][d];
#pragma unroll
        for (int a = 0; a < 4; ++a)
#pragma unroll
            for (int b = 0; b < 4; ++b) {
                float d0 = av[a].x - bv[b].x;
                float d1 = av[a].y - bv[b].y;
                float d2 = av[a].z - bv[b].z;
                float d3 = av[a].w - bv[b].w;
                acc[a][b] = fmaf(d0, d0, acc[a][b]);
                acc[a][b] = fmaf(d1, d1, acc[a][b]);
                acc[a][b] = fmaf(d2, d2, acc[a][b]);
                acc[a][b] = fmaf(d3, d3, acc[a][b]);
            }
    }
#pragma unroll
    for (int a = 0; a < 4; ++a) {
        int i = i0 + ty + 16 * a;
        float* drow = Dst + (size_t)i * N + j0;
#pragma unroll
        for (int b = 0; b < 4; ++b) drow[tx + 16 * b] = acc[a][b];
    }
}

// -------- grid barrier (r10-proven): flag-array + scanner + 16 replicas ------
__device__ __forceinline__ float grid_sync(float* ws, int b, int t, unsigned G,
                                           const float* red2, float* bcast,
                                           bool wake) {
    __syncthreads();  // all lanes' global stores drained before the flag store
    if (t == 0) {
        float s = 0.f;
#pragma unroll
        for (int i = 0; i < WAVES; ++i) s += red2[i];
        unsigned long long pk = (unsigned long long)G |
                                ((unsigned long long)__float_as_uint(s) << 32);
        __hip_atomic_store((unsigned long long*)(ws + WS_FLAGS) + b, pk,
                           __ATOMIC_RELAXED, __HIP_MEMORY_SCOPE_AGENT);
    }
    if (b == 0 && t < 64) {  // scanner wave
        unsigned long long* fl = (unsigned long long*)(ws + WS_FLAGS);
        float sum;
        for (;;) {
            bool ok = true;
            sum = 0.f;
#pragma unroll
            for (int j = 0; j < NBLK / 64; ++j) {
                unsigned long long q =
                    __hip_atomic_load(fl + (t * (NBLK / 64) + j),
                                      __ATOMIC_RELAXED, __HIP_MEMORY_SCOPE_AGENT);
                ok = ok && ((unsigned)q >= G);
                sum += __uint_as_float((unsigned)(q >> 32));
            }
            if (__all(ok)) break;
            __builtin_amdgcn_s_sleep(1);
        }
#pragma unroll
        for (int off = 32; off; off >>= 1) sum += __shfl_xor(sum, off);
        if (wake && t < NREP) {
            unsigned long long pk =
                (unsigned long long)G |
                ((unsigned long long)__float_as_uint(sum) << 32);
            __hip_atomic_store((unsigned long long*)(ws + WS_GGEN) + t * 8, pk,
                               __ATOMIC_RELAXED, __HIP_MEMORY_SCOPE_AGENT);
        }
        if (t == 0) *bcast = sum;
    } else if (t == 0 && wake) {  // b != 0
        unsigned long long* gp =
            (unsigned long long*)(ws + WS_GGEN) + (b & (NREP - 1)) * 8;
        unsigned long long q;
        for (;;) {
            q = __hip_atomic_load(gp, __ATOMIC_RELAXED, __HIP_MEMORY_SCOPE_AGENT);
            if ((unsigned)q >= G) break;
            __builtin_amdgcn_s_sleep(2);
        }
        *bcast = __uint_as_float((unsigned)(q >> 32));
    }
    __syncthreads();
    return *bcast;  // valid when wake (all blocks) or b==0
}

// ------ stage v into LDS by TAG-POLL: consumer-side flow control, no barrier --
// Each thread owns 4 (tag,value) pairs; spins until tag >= tagNeed.
__device__ __forceinline__ void stage_poll(const float* __restrict__ ws,
                                           float* __restrict__ sv, int t,
                                           unsigned tagNeed) {
    const unsigned long long* v8 = (const unsigned long long*)(ws + WS_V);
    unsigned long long q[4];
    bool ok[4] = {false, false, false, false};
    for (;;) {
        bool all = true;
#pragma unroll
        for (int i = 0; i < 4; ++i) {
            if (!ok[i]) {
                q[i] = __hip_atomic_load(v8 + (t + TPB * i), __ATOMIC_RELAXED,
                                         __HIP_MEMORY_SCOPE_AGENT);
                ok[i] = ((unsigned)q[i] >= tagNeed);
            }
            all = all && ok[i];
        }
        if (all) break;
        __builtin_amdgcn_s_sleep(1);
    }
#pragma unroll
    for (int i = 0; i < 4; ++i)
        sv[t + TPB * i] = __uint_as_float((unsigned)(q[i] >> 32));
}

// ---- u-phase: row LSE from the PINNED register row (zero memory traffic) ----
__device__ __forceinline__ float phasePinned(const float4 (&cR)[16],
                                             const float* __restrict__ sv,
                                             int lane, float target) {
    const float4* __restrict__ svv = (const float4*)sv;
    float m = -3.0e38f, s = 0.f;
#pragma unroll
    for (int g = 0; g < 4; ++g) {
        float d[16];
#pragma unroll
        for (int k = 0; k < 4; ++k) {
            float4 w = svv[lane + 64 * (4 * g + k)];
            d[4 * k + 0] = fmaf(cR[4 * g + k].x, -SV_SCALE, w.x);
            d[4 * k + 1] = fmaf(cR[4 * g + k].y, -SV_SCALE, w.y);
            d[4 * k + 2] = fmaf(cR[4 * g + k].z, -SV_SCALE, w.z);
            d[4 * k + 3] = fmaf(cR[4 * g + k].w, -SV_SCALE, w.w);
        }
        float m4[4];
#pragma unroll
        for (int k = 0; k < 4; ++k)
            m4[k] = fmaxf(fmaxf(d[4 * k], d[4 * k + 1]),
                          fmaxf(d[4 * k + 2], d[4 * k + 3]));
        float mg = fmaxf(fmaxf(m4[0], m4[1]), fmaxf(m4[2], m4[3]));
        float mn = fmaxf(m, mg);
        float ps = 0.f;
#pragma unroll
        for (int k = 0; k < 16; ++k) ps += EXP2F(d[k] - mn);
        s = fmaf(s, EXP2F(m - mn), ps);
        m = mn;
    }
#pragma unroll
    for (int off = 32; off; off >>= 1) {
        float mo = __shfl_xor(m, off);
        float so = __shfl_xor(s, off);
        float mn = fmaxf(m, mo);
        s = fmaf(s, EXP2F(m - mn), so * EXP2F(mo - mn));
        m = mn;
    }
    return fmaf(-EPS_LN2, m + LOG2F(s), target);
}

// ---------------- persistent kernel: all iterations + final ----------------
__global__ __launch_bounds__(TPB)
__attribute__((amdgpu_waves_per_eu(4, 4)))  // authorize the 128-VGPR tier
void sinkhorn_persist(
    const float* __restrict__ Cm, float* __restrict__ ws,
    float* __restrict__ out, float target) {
    __shared__ float sv[N];              // 16 KB staged (scaled) v
    __shared__ float4 bufA[WAVES][256];  // 64 KB transpose ping
    __shared__ float4 bufB[WAVES][256];  // 64 KB transpose pong
    __shared__ float us_lds[WAVES];
    __shared__ float red2[WAVES];
    __shared__ float bcast;
    unsigned long long* P8 = (unsigned long long*)(out + 1);  // 2x8MB partials
    unsigned long long* V8 = (unsigned long long*)(ws + WS_V);
    const int t = threadIdx.x;
    const int b = blockIdx.x;
    const int lane = t & 63, wv = t >> 6;
    const int row = (b << 4) + wv;  // this wave's row
    const float targs = target * SV_SCALE;
    unsigned G = 1;
    float errv = 1e30f;
    float uprev = 0.f, un = 0.f;
    unsigned fin = MAX_ITER;  // tag of the final v

    // prologue: load this wave's C row ONCE; pin it for the whole kernel.
    float4 cR[16];
    {
        const float4* __restrict__ crow = (const float4*)(Cm + (size_t)row * N);
#pragma unroll
        for (int k = 0; k < 16; ++k) cR[k] = crow[lane + 64 * k];
#pragma unroll
        for (int k = 0; k < 16; ++k) PIN4(cR[k]);
    }

    for (int it = 0; it < MAX_ITER; ++it) {
        // ---- stage v_{it-1} by tag-poll (replaces old barrier #2) ----
        stage_poll(ws, sv, t, (unsigned)it);
        __syncthreads();

        // ---- u-phase: zero memory traffic ----
        un = phasePinned(cR, sv, lane, target);
        if (lane == 0) {
            red2[wv] = fabsf(un - uprev);  // err contribution
            us_lds[wv] = un * SV_SCALE;    // share scaled u with block
        }
        uprev = un;
        __syncthreads();
        const float usw = us_lds[wv];

        // ---- v-partials: ping-pong LDS transpose -> parity slot (it&1) ----
        unsigned long long* Ps = P8 + (size_t)(it & 1) * N * NBLK;
#pragma unroll
        for (int kk = 0; kk < 4; ++kk) {  // chunk 0 -> bufA
            float4 cc = cR[kk];
            float4 dd;
            dd.x = fmaf(cc.x, -SV_SCALE, usw);
            dd.y = fmaf(cc.y, -SV_SCALE, usw);
            dd.z = fmaf(cc.z, -SV_SCALE, usw);
            dd.w = fmaf(cc.w, -SV_SCALE, usw);
            bufA[wv][lane + 64 * kk] = dd;
        }
        __syncthreads();
        for (int c = 0; c < 4; ++c) {
            const float* bufs = (const float*)((c & 1) ? bufB : bufA);
            float val[16];
#pragma unroll
            for (int w2 = 0; w2 < 16; ++w2) val[w2] = bufs[w2 * 1024 + t];
            if (c < 3) {  // write next chunk to the other buffer meanwhile
                float4(*bw)[256] = (c & 1) ? bufA : bufB;
#pragma unroll
                for (int kk = 0; kk < 4; ++kk) {
                    float4 cc = cR[4 * (c + 1) + kk];
                    float4 dd;
                    dd.x = fmaf(cc.x, -SV_SCALE, usw);
                    dd.y = fmaf(cc.y, -SV_SCALE, usw);
                    dd.z = fmaf(cc.z, -SV_SCALE, usw);
                    dd.w = fmaf(cc.w, -SV_SCALE, usw);
                    bw[wv][lane + 64 * kk] = dd;
                }
            }
            float m = val[0];
#pragma unroll
            for (int w2 = 1; w2 < 16; ++w2) m = fmaxf(m, val[w2]);
            float s = 0.f;
#pragma unroll
            for (int w2 = 0; w2 < 16; ++w2) s += EXP2F(val[w2] - m);
            const int j = c * 1024 + t;  // this thread's column
            unsigned long long pk =
                (unsigned long long)__float_as_uint(m) |
                ((unsigned long long)__float_as_uint(s) << 32);
            __hip_atomic_store(
                Ps + ((size_t)(j >> 4) * NBLK + b) * 16 + (j & 15), pk,
                __ATOMIC_RELAXED, __HIP_MEMORY_SCOPE_AGENT);
            if (c < 3) __syncthreads();  // last chunk: grid_sync entry covers
        }

        // ---- the ONE barrier per iteration: partials visible + err total ----
        errv = grid_sync(ws, b, t, G++, red2, &bcast, true);

        // ---- v-combine: block b owns columns 16b..16b+15; wave wv = one col
        {
            float m = -3.0e38f, s = 0.f;
#pragma unroll
            for (int i = 0; i < 4; ++i) {
                const int bb = lane + 64 * i;
                unsigned long long q = __hip_atomic_load(
                    Ps + ((size_t)b * NBLK + bb) * 16 + wv, __ATOMIC_RELAXED,
                    __HIP_MEMORY_SCOPE_AGENT);
                float mo = __uint_as_float((unsigned)q);
                float so = __uint_as_float((unsigned)(q >> 32));
                float mn = fmaxf(m, mo);
                s = fmaf(s, EXP2F(m - mn), so * EXP2F(mo - mn));
                m = mn;
            }
#pragma unroll
            for (int off = 32; off; off >>= 1) {
                float mo = __shfl_xor(m, off);
                float so = __shfl_xor(s, off);
                float mn = fmaxf(m, mo);
                s = fmaf(s, EXP2F(m - mn), so * EXP2F(mo - mn));
                m = mn;
            }
            if (lane == 0) {
                // scaled domain: vn' = targs - (m + log2 s)
                float vn = targs - (m + LOG2F(s));
                unsigned long long pk =
                    (unsigned long long)(unsigned)(it + 1) |
                    ((unsigned long long)__float_as_uint(vn) << 32);
                __hip_atomic_store(V8 + (16 * b + wv), pk, __ATOMIC_RELAXED,
                                   __HIP_MEMORY_SCOPE_AGENT);  // tag it+1
                red2[wv] = 0.f;
            }
        }
        fin = (unsigned)(it + 1);
        // reference latches done AFTER applying this iteration's updates.
        if (errv < THRESH) break;  // uniform: same payload sum everywhere
    }

    // ---- final: pi = exp((u_i + v_j - C_ij)/eps), cost = sum(pi*C) ----
    // Poll v_final by tag (all combines done => all partial reads done =>
    // pi writes may safely clobber the partials region).
    stage_poll(ws, sv, t, fin);
    __syncthreads();
    {
        float* pi = out + 1;
        const float ui = un * SV_SCALE;  // exp2-domain
        float4* __restrict__ prow = (float4*)(pi + (size_t)row * N);
        const float4* __restrict__ svv = (const float4*)sv;
        float csum = 0.f;
#pragma unroll
        for (int k = 0; k < 16; ++k) {
            const int f = lane + 64 * k;
            float4 c = cR[k];
            float4 w = svv[f];
            float4 p;
            p.x = EXP2F(fmaf(c.x, -SV_SCALE, ui + w.x));
            p.y = EXP2F(fmaf(c.y, -SV_SCALE, ui + w.y));
            p.z = EXP2F(fmaf(c.z, -SV_SCALE, ui + w.z));
            p.w = EXP2F(fmaf(c.w, -SV_SCALE, ui + w.w));
            prow[f] = p;
            csum = fmaf(p.x, c.x, csum);
            csum = fmaf(p.y, c.y, csum);
            csum = fmaf(p.z, c.z, csum);
            csum = fmaf(p.w, c.w, csum);
        }
#pragma unroll
        for (int off = 32; off; off >>= 1) csum += __shfl_xor(csum, off);
        if (lane == 0) red2[wv] = csum;
    }
    // cost rides the final barrier payload; only the scanner needs the total.
    float ctot = grid_sync(ws, b, t, G++, red2, &bcast, false);
    if (b == 0 && t == 0) out[0] = ctot;
}

extern "C" void kernel_launch(void* const* d_in, const int* in_sizes, int n_in,
                              void* d_out, int out_size, void* d_ws, size_t ws_size,
                              hipStream_t stream) {
    const float* x = (const float*)d_in[0];  // [4096,64]
    const float* y = (const float*)d_in[1];  // [4096,64]
    float* out = (float*)d_out;              // [0]=cost, [1..N*N]=pi, [1+N*N..]=C
    float* C = out + 1 + (size_t)N * N;
    float* ws = (float*)d_ws;

    init_ws<<<dim3((WS_TOTAL + 255) / 256), dim3(256), 0, stream>>>(ws);

    dim3 bgrid(64, 64);
    build_dist<<<bgrid, dim3(256), 0, stream>>>(x, y, C);  // C[i][j] only

    float target = EPS * logf(1.0f / (float)N + 1e-8f);  // == eps*log_mu == eps*log_nu

    sinkhorn_persist<<<dim3(NBLK), dim3(TPB), 0, stream>>>(C, ws, out, target);
}

// Round 13
// 871.995 us; speedup vs baseline: 1.2930x; 1.1935x over previous
//
#include <hip/hip_runtime.h>
#include <math.h>

#define N 4096
#define DIM 64
#define MAX_ITER 50
#define EPS 0.1f
#define THRESH 0.1f

// exp2/log2 domain constants. SV_SCALE * EPS_LN2 == 1 (exact): v is kept
// PRE-SCALED; combine epilogue is targs - (m + log2 s).
#define SV_SCALE 14.4269504088896340f  // (1/eps) * log2(e)
#define EPS_LN2 0.0693147180559945f    // eps * ln(2)

// gfx950 native transcendentals: v_exp_f32 IS 2^x, v_log_f32 IS log2
#define EXP2F(x) __builtin_amdgcn_exp2f(x)
#define LOG2F(x) __builtin_amdgcn_logf(x)

// 256 blocks x 1024 threads (16 waves), wave-per-row, 16 rows/block, 1 block/CU.
// r10-proven structure: pinned C rows, two two-hop barriers/iter. This round's
// delta: partials are scalar block-LSEs (L_b = m + log2 s, 4B) -- LSE is
// associative over partial LSEs, so combine = LSE of 256 scalars. Halves both
// partial write and read traffic vs (m,s) pairs.
#define NBLK 256
#define TPB 1024
#define WAVES 16
#define NREP 16  // wake replicas

// ws layout (floats): v[4096] (scaled domain) + flags + replicas.
#define WS_V 0
#define WS_FLAGS N                    // 256 x (u32 gen, f32 val) 8B pairs
#define WS_GGEN (N + 2 * NBLK)        // 16 replicas x 16-word stride
#define WS_TOTAL (N + 2 * NBLK + NREP * 16)

// opaque keep-alive: values become non-rematerializable register residents
#define PIN4(v) asm volatile("" : "+v"(v.x), "+v"(v.y), "+v"(v.z), "+v"(v.w))

// ---------------- init: zero v + flags + replicas ----------------
__global__ void init_ws(float* __restrict__ ws) {
    int i = blockIdx.x * 256 + threadIdx.x;
    if (i < WS_TOTAL) ws[i] = 0.0f;
}

// ---------------- build D[i][j] = sum_d (A[i][d]-B[j][d])^2 ----------------
__global__ __launch_bounds__(256) void build_dist(const float* __restrict__ A,
                                                  const float* __restrict__ B,
                                                  float* __restrict__ Dst) {
    __shared__ float As[64][68];
    __shared__ float Bs[64][68];
    const int i0 = blockIdx.y << 6, j0 = blockIdx.x << 6;
    const int t = threadIdx.x;
    const float* Ag = A + (size_t)i0 * DIM;
    const float* Bg = B + (size_t)j0 * DIM;
    for (int k = t; k < 4096; k += 256) {
        As[k >> 6][k & 63] = Ag[k];
        Bs[k >> 6][k & 63] = Bg[k];
    }
    __syncthreads();
    const int ty = t >> 4, tx = t & 15;
    float acc[4][4] = {{0.f}};
    for (int d = 0; d < DIM; d += 4) {
        float4 av[4], bv[4];
#pragma unroll
        for (int a = 0; a < 4; ++a) av[a] = *(const float4*)&As[ty + 16 * a][d];
#pragma unroll
        for (int b = 0; b < 4; ++b) bv[b] = *(const float4*)&Bs[tx + 16 * b][d];
#pragma unroll
        for (int a = 0; a < 4; ++a)
#pragma unroll
            for (int b = 0; b < 4; ++b) {
                float d0 = av[a].x - bv[b].x;
                float d1 = av[a].y - bv[b].y;
                float d2 = av[a].z - bv[b].z;
                float d3 = av[a].w - bv[b].w;
                acc[a][b] = fmaf(d0, d0, acc[a][b]);
                acc[a][b] = fmaf(d1, d1, acc[a][b]);
                acc[a][b] = fmaf(d2, d2, acc[a][b]);
                acc[a][b] = fmaf(d3, d3, acc[a][b]);
            }
    }
#pragma unroll
    for (int a = 0; a < 4; ++a) {
        int i = i0 + ty + 16 * a;
        float* drow = Dst + (size_t)i * N + j0;
#pragma unroll
        for (int b = 0; b < 4; ++b) drow[tx + 16 * b] = acc[a][b];
    }
}

// -------- grid barrier (r10-proven): flag-array + scanner + 16 replicas ------
__device__ __forceinline__ float grid_sync(float* ws, int b, int t, unsigned G,
                                           const float* red2, float* bcast,
                                           bool wake) {
    __syncthreads();  // all lanes' global stores drained before the flag store
    if (t == 0) {
        float s = 0.f;
#pragma unroll
        for (int i = 0; i < WAVES; ++i) s += red2[i];
        unsigned long long pk = (unsigned long long)G |
                                ((unsigned long long)__float_as_uint(s) << 32);
        __hip_atomic_store((unsigned long long*)(ws + WS_FLAGS) + b, pk,
                           __ATOMIC_RELAXED, __HIP_MEMORY_SCOPE_AGENT);
    }
    if (b == 0 && t < 64) {  // scanner wave
        unsigned long long* fl = (unsigned long long*)(ws + WS_FLAGS);
        float sum;
        for (;;) {
            bool ok = true;
            sum = 0.f;
#pragma unroll
            for (int j = 0; j < NBLK / 64; ++j) {
                unsigned long long q =
                    __hip_atomic_load(fl + (t * (NBLK / 64) + j),
                                      __ATOMIC_RELAXED, __HIP_MEMORY_SCOPE_AGENT);
                ok = ok && ((unsigned)q >= G);
                sum += __uint_as_float((unsigned)(q >> 32));
            }
            if (__all(ok)) break;
            __builtin_amdgcn_s_sleep(1);
        }
#pragma unroll
        for (int off = 32; off; off >>= 1) sum += __shfl_xor(sum, off);
        if (wake && t < NREP) {
            unsigned long long pk =
                (unsigned long long)G |
                ((unsigned long long)__float_as_uint(sum) << 32);
            __hip_atomic_store((unsigned long long*)(ws + WS_GGEN) + t * 8, pk,
                               __ATOMIC_RELAXED, __HIP_MEMORY_SCOPE_AGENT);
        }
        if (t == 0) *bcast = sum;
    } else if (t == 0 && wake) {  // b != 0
        unsigned long long* gp =
            (unsigned long long*)(ws + WS_GGEN) + (b & (NREP - 1)) * 8;
        unsigned long long q;
        for (;;) {
            q = __hip_atomic_load(gp, __ATOMIC_RELAXED, __HIP_MEMORY_SCOPE_AGENT);
            if ((unsigned)q >= G) break;
            __builtin_amdgcn_s_sleep(2);
        }
        *bcast = __uint_as_float((unsigned)(q >> 32));
    }
    __syncthreads();
    return *bcast;  // valid when wake (all blocks) or b==0
}

// ------- stage the (pre-scaled) v vector into LDS: pure copy -------
__device__ __forceinline__ void stage(const float* __restrict__ ws,
                                      float* __restrict__ sv, int t) {
    const unsigned long long* s8 = (const unsigned long long*)(ws + WS_V);
#pragma unroll
    for (int i = 0; i < 2; ++i) {
        int idx = t + TPB * i;  // 0..2047
        unsigned long long q = __hip_atomic_load(s8 + idx, __ATOMIC_RELAXED,
                                                 __HIP_MEMORY_SCOPE_AGENT);
        sv[2 * idx] = __uint_as_float((unsigned)q);
        sv[2 * idx + 1] = __uint_as_float((unsigned)(q >> 32));
    }
}

// ---- u-phase: row LSE from the PINNED register row (zero memory traffic) ----
__device__ __forceinline__ float phasePinned(const float4 (&cR)[16],
                                             const float* __restrict__ sv,
                                             int lane, float target) {
    const float4* __restrict__ svv = (const float4*)sv;
    float m = -3.0e38f, s = 0.f;
#pragma unroll
    for (int g = 0; g < 4; ++g) {
        float d[16];
#pragma unroll
        for (int k = 0; k < 4; ++k) {
            float4 w = svv[lane + 64 * (4 * g + k)];
            d[4 * k + 0] = fmaf(cR[4 * g + k].x, -SV_SCALE, w.x);
            d[4 * k + 1] = fmaf(cR[4 * g + k].y, -SV_SCALE, w.y);
            d[4 * k + 2] = fmaf(cR[4 * g + k].z, -SV_SCALE, w.z);
            d[4 * k + 3] = fmaf(cR[4 * g + k].w, -SV_SCALE, w.w);
        }
        float m4[4];
#pragma unroll
        for (int k = 0; k < 4; ++k)
            m4[k] = fmaxf(fmaxf(d[4 * k], d[4 * k + 1]),
                          fmaxf(d[4 * k + 2], d[4 * k + 3]));
        float mg = fmaxf(fmaxf(m4[0], m4[1]), fmaxf(m4[2], m4[3]));
        float mn = fmaxf(m, mg);
        float ps = 0.f;
#pragma unroll
        for (int k = 0; k < 16; ++k) ps += EXP2F(d[k] - mn);
        s = fmaf(s, EXP2F(m - mn), ps);
        m = mn;
    }
#pragma unroll
    for (int off = 32; off; off >>= 1) {
        float mo = __shfl_xor(m, off);
        float so = __shfl_xor(s, off);
        float mn = fmaxf(m, mo);
        s = fmaf(s, EXP2F(m - mn), so * EXP2F(mo - mn));
        m = mn;
    }
    return fmaf(-EPS_LN2, m + LOG2F(s), target);
}

// ---------------- persistent kernel: all iterations + final ----------------
__global__ __launch_bounds__(TPB)
__attribute__((amdgpu_waves_per_eu(4, 4)))  // authorize the 128-VGPR tier
void sinkhorn_persist(
    const float* __restrict__ Cm, float* __restrict__ ws,
    float* __restrict__ out, float target) {
    __shared__ float sv[N];              // 16 KB staged (scaled) v
    __shared__ float4 bufA[WAVES][256];  // 64 KB transpose ping
    __shared__ float4 bufB[WAVES][256];  // 64 KB transpose pong
    __shared__ float us_lds[WAVES];
    __shared__ float red2[WAVES];
    __shared__ float bcast;
    float* v = ws + WS_V;
    float* P4 = out + 1;  // 4 MB scalar block-LSE partials (dead pi region)
    const int t = threadIdx.x;
    const int b = blockIdx.x;
    const int lane = t & 63, wv = t >> 6;
    const int row = (b << 4) + wv;  // this wave's row
    const float targs = target * SV_SCALE;
    unsigned G = 1;
    float errv = 1e30f;
    float uprev = 0.f, un = 0.f;

    // prologue: load this wave's C row ONCE; pin it for the whole kernel.
    float4 cR[16];
    {
        const float4* __restrict__ crow = (const float4*)(Cm + (size_t)row * N);
#pragma unroll
        for (int k = 0; k < 16; ++k) cR[k] = crow[lane + 64 * k];
#pragma unroll
        for (int k = 0; k < 16; ++k) PIN4(cR[k]);
    }

    for (int it = 0; it < MAX_ITER; ++it) {
        // ---- u-phase: zero memory traffic ----
        stage(ws, sv, t);
        __syncthreads();
        un = phasePinned(cR, sv, lane, target);
        if (lane == 0) {
            red2[wv] = fabsf(un - uprev);  // err contribution
            us_lds[wv] = un * SV_SCALE;    // share scaled u with block
        }
        uprev = un;
        __syncthreads();
        const float usw = us_lds[wv];

        // ---- v-partials: ping-pong LDS transpose; store scalar block-LSE ----
#pragma unroll
        for (int kk = 0; kk < 4; ++kk) {  // chunk 0 -> bufA
            float4 cc = cR[kk];
            float4 dd;
            dd.x = fmaf(cc.x, -SV_SCALE, usw);
            dd.y = fmaf(cc.y, -SV_SCALE, usw);
            dd.z = fmaf(cc.z, -SV_SCALE, usw);
            dd.w = fmaf(cc.w, -SV_SCALE, usw);
            bufA[wv][lane + 64 * kk] = dd;
        }
        __syncthreads();
        for (int c = 0; c < 4; ++c) {
            const float* bufs = (const float*)((c & 1) ? bufB : bufA);
            float val[16];
#pragma unroll
            for (int w2 = 0; w2 < 16; ++w2) val[w2] = bufs[w2 * 1024 + t];
            if (c < 3) {  // write next chunk to the other buffer meanwhile
                float4(*bw)[256] = (c & 1) ? bufA : bufB;
#pragma unroll
                for (int kk = 0; kk < 4; ++kk) {
                    float4 cc = cR[4 * (c + 1) + kk];
                    float4 dd;
                    dd.x = fmaf(cc.x, -SV_SCALE, usw);
                    dd.y = fmaf(cc.y, -SV_SCALE, usw);
                    dd.z = fmaf(cc.z, -SV_SCALE, usw);
                    dd.w = fmaf(cc.w, -SV_SCALE, usw);
                    bw[wv][lane + 64 * kk] = dd;
                }
            }
            float m = val[0];
#pragma unroll
            for (int w2 = 1; w2 < 16; ++w2) m = fmaxf(m, val[w2]);
            float s = 0.f;
#pragma unroll
            for (int w2 = 0; w2 < 16; ++w2) s += EXP2F(val[w2] - m);
            const int j = c * 1024 + t;  // this thread's column
            // scalar block-LSE: L = m + log2(s)  (LSE is associative)
            __hip_atomic_store(
                P4 + ((size_t)(j >> 4) * NBLK + b) * 16 + (j & 15),
                m + LOG2F(s), __ATOMIC_RELAXED, __HIP_MEMORY_SCOPE_AGENT);
            if (c < 3) __syncthreads();  // last chunk: grid_sync entry covers
        }
        errv = grid_sync(ws, b, t, G++, red2, &bcast, true);  // barrier 1

        // ---- v-combine: LSE over 256 scalar partials per owned column ----
        {
            float L[4];
#pragma unroll
            for (int i = 0; i < 4; ++i)
                L[i] = __hip_atomic_load(
                    P4 + ((size_t)b * NBLK + (lane + 64 * i)) * 16 + wv,
                    __ATOMIC_RELAXED, __HIP_MEMORY_SCOPE_AGENT);
            float m = fmaxf(fmaxf(L[0], L[1]), fmaxf(L[2], L[3]));
            float s = EXP2F(L[0] - m) + EXP2F(L[1] - m) + EXP2F(L[2] - m) +
                      EXP2F(L[3] - m);
#pragma unroll
            for (int off = 32; off; off >>= 1) {
                float mo = __shfl_xor(m, off);
                float so = __shfl_xor(s, off);
                float mn = fmaxf(m, mo);
                s = fmaf(s, EXP2F(m - mn), so * EXP2F(mo - mn));
                m = mn;
            }
            if (lane == 0) {
                // scaled domain: vn' = targs - (m + log2 s)
                float vn = targs - (m + LOG2F(s));
                __hip_atomic_store(&v[16 * b + wv], vn, __ATOMIC_RELAXED,
                                   __HIP_MEMORY_SCOPE_AGENT);
                red2[wv] = 0.f;
            }
        }
        grid_sync(ws, b, t, G++, red2, &bcast, true);  // barrier 2: v visible
        // reference latches done AFTER applying this iteration's updates.
        if (errv < THRESH) break;  // uniform: same payload sum everywhere
    }

    // ---- final: pi = exp((u_i + v_j - C_ij)/eps), cost = sum(pi*C) ----
    // cR pinned; un is this wave's final u (all lanes). Partials region is
    // dead (all combine reads done before barrier 2); pi stores overwrite it.
    stage(ws, sv, t);
    __syncthreads();
    {
        float* pi = out + 1;
        const float ui = un * SV_SCALE;  // exp2-domain
        float4* __restrict__ prow = (float4*)(pi + (size_t)row * N);
        const float4* __restrict__ svv = (const float4*)sv;
        float csum = 0.f;
#pragma unroll
        for (int k = 0; k < 16; ++k) {
            const int f = lane + 64 * k;
            float4 c = cR[k];
            float4 w = svv[f];
            float4 p;
            p.x = EXP2F(fmaf(c.x, -SV_SCALE, ui + w.x));
            p.y = EXP2F(fmaf(c.y, -SV_SCALE, ui + w.y));
            p.z = EXP2F(fmaf(c.z, -SV_SCALE, ui + w.z));
            p.w = EXP2F(fmaf(c.w, -SV_SCALE, ui + w.w));
            prow[f] = p;
            csum = fmaf(p.x, c.x, csum);
            csum = fmaf(p.y, c.y, csum);
            csum = fmaf(p.z, c.z, csum);
            csum = fmaf(p.w, c.w, csum);
        }
#pragma unroll
        for (int off = 32; off; off >>= 1) csum += __shfl_xor(csum, off);
        if (lane == 0) red2[wv] = csum;
    }
    // cost rides the final barrier payload; only the scanner needs the total.
    float ctot = grid_sync(ws, b, t, G++, red2, &bcast, false);
    if (b == 0 && t == 0) out[0] = ctot;
}

extern "C" void kernel_launch(void* const* d_in, const int* in_sizes, int n_in,
                              void* d_out, int out_size, void* d_ws, size_t ws_size,
                              hipStream_t stream) {
    const float* x = (const float*)d_in[0];  // [4096,64]
    const float* y = (const float*)d_in[1];  // [4096,64]
    float* out = (float*)d_out;              // [0]=cost, [1..N*N]=pi, [1+N*N..]=C
    float* C = out + 1 + (size_t)N * N;
    float* ws = (float*)d_ws;

    init_ws<<<dim3((WS_TOTAL + 255) / 256), dim3(256), 0, stream>>>(ws);

    dim3 bgrid(64, 64);
    build_dist<<<bgrid, dim3(256), 0, stream>>>(x, y, C);  // C[i][j] only

    float target = EPS * logf(1.0f / (float)N + 1e-8f);  // == eps*log_mu == eps*log_nu

    sinkhorn_persist<<<dim3(NBLK), dim3(TPB), 0, stream>>>(C, ws, out, target);
}